// Round 11
// baseline (95.281 us; speedup 1.0000x reference)
//
#include <hip/hip_runtime.h>

typedef __attribute__((ext_vector_type(4))) float f32x4;
typedef __attribute__((ext_vector_type(8))) short bf16x8;
typedef __attribute__((ext_vector_type(4))) unsigned int u32x4;

#define IDIM    128
#define HID     64
#define TDEPTH  6
#define WROWS   32                       // rows per wave
#define NWAVES  4
#define BLOCK   (NWAVES * 64)            // 256
#define MROWS   (WROWS * NWAVES)         // 128 rows per block
#define NODE_ELEMS 8192                  // shorts per node A-fragment slice (16 KB)
#define HALF_ELEMS (3 * NODE_ELEMS)      // 48 KB per 3-node half
#define WFRAG_ELEMS (TDEPTH * NODE_ELEMS)
#define HALF_VEC (HALF_ELEMS * 2 / 16 / BLOCK)   // 12 u32x4 per thread per half

__device__ __forceinline__ unsigned short f2bf(float f) {
    unsigned int u = __builtin_bit_cast(unsigned int, f);
    unsigned int r = (u + 0x7FFFu + ((u >> 16) & 1u)) >> 16;  // RNE
    return (unsigned short)r;
}

__device__ __forceinline__ unsigned int f2bf_pk(float f0, float f1) {
    unsigned int u0 = __builtin_bit_cast(unsigned int, f0);
    unsigned int u1 = __builtin_bit_cast(unsigned int, f1);
    unsigned int t0 = u0 + 0x7FFFu + ((u0 >> 16) & 1u);
    unsigned int t1 = u1 + 0x7FFFu + ((u1 >> 16) & 1u);
    return (t1 & 0xFFFF0000u) | (t0 >> 16);
}

// Pre-convert W1 (6 chain nodes) into bf16 MFMA **A**-fragment layout of W1^T
// (swapped-GEMM: C[hid,brow] = W1T . xT). A-frag: lane holds
// A[m = ht*16 + (lane&15)][k = ks*32 + (lane>>4)*8 + j] = W1[node][k][hid].
// In-node order: (ht, ks) -> offset (ht*4+ks)*512 + lane*8 + j.
__global__ void prep_wfrag(const float* __restrict__ W1, unsigned short* __restrict__ wfrag) {
    int idx = blockIdx.x * 256 + threadIdx.x;
    if (idx >= WFRAG_ELEMS) return;
    int j    = idx & 7;
    int lane = (idx >> 3) & 63;
    int ks   = (idx >> 9) & 3;
    int ht   = (idx >> 11) & 3;
    int nd   = idx >> 13;
    int node = (1 << nd) - 1;              // chain node: 0,1,3,7,15,31
    int k    = ks * 32 + (lane >> 4) * 8 + j;
    int hid  = ht * 16 + (lane & 15);
    wfrag[idx] = f2bf(W1[((size_t)node * IDIM + k) * HID + hid]);
}

// Round-11 = Round-10's swapped-GEMM (proven: epilogue lane-local, p in regs,
// fold in-lane; kernel ~25us) + occupancy/overlap fix. R10's 96 KB monolithic
// stage forced 1 block/CU (R3 lesson repeated): the single barrier exposed the
// slowest wave's HBM tail to all waves with no co-resident block to overlap.
// Here: bs = ONE 48 KB buffer holding 3 nodes; two halves staged in sequence.
// Half B's 12 dwordx4 are issued into REGISTERS right after the x burst (T14
// split: HBM latency hides under half-A staging + nodes-0..2 compute), then
// ds_written after bar2. LDS ~51 KB, grid 512 -> 2-3 blocks/CU resident.
template <bool USE_WS>
__global__ __launch_bounds__(BLOCK, 3)
void sdt_kernel(const float* __restrict__ x, const float* __restrict__ W1,
                const float* __restrict__ b1, const float* __restrict__ W2,
                const float* __restrict__ b2, const float* __restrict__ leaf,
                const unsigned short* __restrict__ wfrag, float* __restrict__ out) {
    __shared__ __align__(16) unsigned short bs[HALF_ELEMS];   // 48 KB, reused
    __shared__ float b1s[TDEPTH][HID];
    __shared__ float w2s[TDEPTH][HID];
    __shared__ float b2s[8];
    __shared__ float leaf_lds[64];

    const int tid  = threadIdx.x;
    const int wave = tid >> 6;
    const int lane = tid & 63;
    const int lcol = lane & 15;
    const int lq   = lane >> 4;
    const int m0   = blockIdx.x * MROWS + wave * WROWS;

    // ---- x B-frags: lane holds x[m0 + bg*16 + lcol][ks*32 + lq*8 + j] ----
    // (bit-identical addresses/contents to R7's proven A-path; one burst)
    const float* xb = x + (size_t)(m0 + lcol) * IDIM + lq * 8;
    float4 araw[2][4][2];
    #pragma unroll
    for (int bg = 0; bg < 2; bg++)
        #pragma unroll
        for (int ks = 0; ks < 4; ks++) {
            const float4* ap = reinterpret_cast<const float4*>(
                xb + (size_t)(bg * 16) * IDIM + ks * 32);
            araw[bg][ks][0] = ap[0];
            araw[bg][ks][1] = ap[1];
        }

    // ---- half-B stage loads -> REGISTERS now (T14 issue-early/write-late);
    //      latency hides under half-A staging + nodes 0-2 compute ----
    u32x4 sB[HALF_VEC];
    if (USE_WS) {
        const u32x4* srcB = reinterpret_cast<const u32x4*>(wfrag + HALF_ELEMS);
        #pragma unroll
        for (int i = 0; i < HALF_VEC; i++) sB[i] = srcB[tid + i * BLOCK];
    }

    // ---- stage half A (nodes 0-2) into LDS ----
    if (USE_WS) {
        const u32x4* srcA = reinterpret_cast<const u32x4*>(wfrag);
        u32x4* dst = reinterpret_cast<u32x4*>(&bs[0]);
        #pragma unroll
        for (int i = 0; i < HALF_VEC; i++) dst[tid + i * BLOCK] = srcA[tid + i * BLOCK];
    } else {
        for (int e = tid; e < HALF_ELEMS; e += BLOCK) {
            int j = e & 7, ln = (e >> 3) & 63, ks = (e >> 9) & 3,
                ht = (e >> 11) & 3, nd = e >> 13;
            int node = (1 << nd) - 1;
            int k    = ks * 32 + (ln >> 4) * 8 + j;
            int hid  = ht * 16 + (ln & 15);
            bs[e] = f2bf(W1[((size_t)node * IDIM + k) * HID + hid]);
        }
    }

    // ---- epilogue params + leaf (once) ----
    for (int i = tid; i < TDEPTH * HID; i += BLOCK) {
        int nd = i >> 6, col = i & 63, node = (1 << nd) - 1;
        b1s[nd][col] = b1[node * HID + col];
        w2s[nd][col] = W2[node * HID + col];
    }
    if (tid < 6)  b2s[tid] = b2[(1 << tid) - 1];
    if (tid < 64) leaf_lds[tid] = leaf[tid];

    // ---- convert x to bf16 B-frags ----
    bf16x8 xfrag[2][4];
    #pragma unroll
    for (int bg = 0; bg < 2; bg++)
        #pragma unroll
        for (int ks = 0; ks < 4; ks++) {
            float4 v0 = araw[bg][ks][0], v1 = araw[bg][ks][1];
            u32x4 pk;
            pk[0] = f2bf_pk(v0.x, v0.y);
            pk[1] = f2bf_pk(v0.z, v0.w);
            pk[2] = f2bf_pk(v1.x, v1.y);
            pk[3] = f2bf_pk(v1.z, v1.w);
            xfrag[bg][ks] = __builtin_bit_cast(bf16x8, pk);
        }

    __syncthreads();                       // bar1: half A + params ready

    float pq[2][TDEPTH];                   // p per brow-group per node (static idx)

    // ---- compute one node: swapped GEMM C[hid,brow] + lane-local epilogue ----
    auto compute = [&](int nd, int ndl) {
        f32x4 acc[2][4];                   // [bg][ht]
        #pragma unroll
        for (int bg = 0; bg < 2; bg++)
            #pragma unroll
            for (int ht = 0; ht < 4; ht++)
                acc[bg][ht] = (f32x4){0.f, 0.f, 0.f, 0.f};
        #pragma unroll
        for (int ks = 0; ks < 4; ks++) {
            bf16x8 awf[4];
            #pragma unroll
            for (int ht = 0; ht < 4; ht++)
                awf[ht] = *reinterpret_cast<const bf16x8*>(
                    &bs[(ndl * 16 + ht * 4 + ks) * 512 + lane * 8]);
            #pragma unroll
            for (int bg = 0; bg < 2; bg++)
                #pragma unroll
                for (int ht = 0; ht < 4; ht++)
                    acc[bg][ht] = __builtin_amdgcn_mfma_f32_16x16x32_bf16(
                        awf[ht], xfrag[bg][ks], acc[bg][ht], 0, 0, 0);
        }
        // lane holds h[brow = bg*16 + lcol][hid = ht*16 + lq*4 + r]
        f32x4 b1q[4], w2q[4];
        #pragma unroll
        for (int ht = 0; ht < 4; ht++) {
            b1q[ht] = *reinterpret_cast<const f32x4*>(&b1s[nd][ht * 16 + lq * 4]);
            w2q[ht] = *reinterpret_cast<const f32x4*>(&w2s[nd][ht * 16 + lq * 4]);
        }
        const float bias2 = b2s[nd];
        #pragma unroll
        for (int bg = 0; bg < 2; bg++) {
            float s = 0.f;
            #pragma unroll
            for (int ht = 0; ht < 4; ht++)
                #pragma unroll
                for (int r = 0; r < 4; r++) {
                    float v = acc[bg][ht][r] + b1q[ht][r];
                    v = v > 0.f ? v : 0.f;
                    s += v * w2q[ht][r];
                }
            s += __shfl_xor(s, 16, 64);    // combine the 4 lq groups
            s += __shfl_xor(s, 32, 64);
            pq[bg][nd] = 1.f / (1.f + __expf(-(s + bias2)));
        }
    };

    compute(0, 0); compute(1, 1); compute(2, 2);
    __syncthreads();                       // bar2: all waves done reading half A

    // ---- write half B (regs -> LDS) ----
    if (USE_WS) {
        u32x4* dst = reinterpret_cast<u32x4*>(&bs[0]);
        #pragma unroll
        for (int i = 0; i < HALF_VEC; i++) dst[tid + i * BLOCK] = sB[i];
    } else {
        for (int e = tid; e < HALF_ELEMS; e += BLOCK) {
            int j = e & 7, ln = (e >> 3) & 63, ks = (e >> 9) & 3,
                ht = (e >> 11) & 3, nd = e >> 13;
            int node = (1 << (nd + 3)) - 1;
            int k    = ks * 32 + (ln >> 4) * 8 + j;
            int hid  = ht * 16 + (ln & 15);
            bs[e] = f2bf(W1[((size_t)node * IDIM + k) * HID + hid]);
        }
    }
    __syncthreads();                       // bar3: half B ready

    compute(3, 0); compute(4, 1); compute(5, 2);

    // ---- fold: fully in-lane (p in regs; leaf via LDS broadcast) ----
    #pragma unroll
    for (int bg = 0; bg < 2; bg++) {
        float q0 = pq[bg][0], q1 = pq[bg][1], q2 = pq[bg][2];
        float q3 = pq[bg][3], p4 = pq[bg][4], p5 = pq[bg][5];
        float acc_out = 0.f;
        #pragma unroll
        for (int ch = 0; ch < 4; ch++) {
            float f4 = (ch & 1) ? p4 : 1.f - p4;
            float f5 = (ch & 2) ? p5 : 1.f - p5;
            const float* lf = leaf_lds + ch * 16;
            float tt[8];
            #pragma unroll
            for (int j = 0; j < 8; j++) {
                float a = lf[2 * j], b = lf[2 * j + 1];
                tt[j] = a + q0 * (b - a);
            }
            #pragma unroll
            for (int j = 0; j < 4; j++) tt[j] = tt[2 * j] + q1 * (tt[2 * j + 1] - tt[2 * j]);
            #pragma unroll
            for (int j = 0; j < 2; j++) tt[j] = tt[2 * j] + q2 * (tt[2 * j + 1] - tt[2 * j]);
            float s = tt[0] + q3 * (tt[1] - tt[0]);
            acc_out += f4 * f5 * s;
        }
        if (lq == 0)                        // lanes 0-15: coalesced 64B store
            out[(size_t)m0 + bg * 16 + lcol] = acc_out;
    }
}

extern "C" void kernel_launch(void* const* d_in, const int* in_sizes, int n_in,
                              void* d_out, int out_size, void* d_ws, size_t ws_size,
                              hipStream_t stream) {
    const float* x    = (const float*)d_in[0];
    const float* W1   = (const float*)d_in[1];
    const float* b1   = (const float*)d_in[2];
    const float* W2   = (const float*)d_in[3];
    const float* b2   = (const float*)d_in[4];
    const float* leaf = (const float*)d_in[5];
    float* out = (float*)d_out;

    const int Bn = in_sizes[0] / IDIM;               // 65536 rows
    const int nblocks = Bn / MROWS;                  // 512 — 2-3 blocks/CU

    if (ws_size >= (size_t)WFRAG_ELEMS * sizeof(unsigned short)) {
        unsigned short* wfrag = (unsigned short*)d_ws;
        prep_wfrag<<<(WFRAG_ELEMS + 255) / 256, 256, 0, stream>>>(W1, wfrag);
        sdt_kernel<true><<<nblocks, BLOCK, 0, stream>>>(x, W1, b1, W2, b2, leaf, wfrag, out);
    } else {
        sdt_kernel<false><<<nblocks, BLOCK, 0, stream>>>(x, W1, b1, W2, b2, leaf, nullptr, out);
    }
}